// Round 3
// baseline (240.903 us; speedup 1.0000x reference)
//
#include <hip/hip_runtime.h>
#include <hip/hip_bf16.h>

// XDeepFM CIN, fused 2-layer MFMA kernel for gfx950 — v3.
// Layer 0: M=131072 (b,d) rows, K = 40i x 48j = 1920 (60 slices), N=128.
// Layer 1: M=131072, K = 39i x 64j = 2496 exact (78 slices), N=128.
// LDS: V f32 [128][41] (20992B) + Z bf16 [128 rows][208B pitch] (26624B) = 47616B
//      -> 3 blocks/CU.  H bf16 [128][68] ALIASES the Z region between layers.
// Z-gen uses v_cvt_pk_bf16_f32 + b128 writes; Z swizzled by XOR bit4 of (row>>3)&1.

using short8 = __attribute__((ext_vector_type(8))) short;
using f32x4  = __attribute__((ext_vector_type(4))) float;

#define VSTR    41                    // f32 elems per V row (41 words: odd -> conflict-free)
#define V_BYTES (128 * VSTR * 4)      // 20992
#define ZPITCH  208                   // bytes per Z row (52 words == 20 mod 32 -> 2-way only)
#define Z_BYTES (128 * ZPITCH)        // 26624
#define SMEM_BYTES (V_BYTES + Z_BYTES)  // 47616 -> 3 blocks/CU
#define HSTR    68                    // bf16 per H row (34 words -> 2-way hj reads)

#define NS0 60                        // layer-0 K slices (1920/32)
#define NS1 78                        // layer-1 K slices (2496/32)
#define NFRAG ((NS0 + NS1) * 8 * 64)  // 70656 packed-B fragments (8 bf16 each)

__device__ __forceinline__ unsigned short f2bf(float x) {
  __hip_bfloat16 h = __float2bfloat16(x);
  return __builtin_bit_cast(unsigned short, h);
}
// packed f32x2 -> bf16x2 (dst.lo = bf16(lo), dst.hi = bf16(hi))
__device__ __forceinline__ unsigned cvt2(float lo, float hi) {
  unsigned r;
  asm("v_cvt_pk_bf16_f32 %0, %1, %2" : "=v"(r) : "v"(lo), "v"(hi));
  return r;
}

// ---------------- W pre-pack: one 8-elem B-fragment per thread (coalesced 16B writes) ----
// Fragment order: slice s, n-block nb, lane l holds W[k=32s+(l>>4)*8+ii][n=nb*16+(l&15)].
__global__ void pack_w(const float* __restrict__ W0, const float* __restrict__ W1,
                       short8* __restrict__ wpk) {
  int fid = blockIdx.x * 256 + threadIdx.x;
  if (fid >= NFRAG) return;
  int lane = fid & 63;
  int t2 = fid >> 6;
  int nb = t2 & 7, s = t2 >> 3;         // s in [0,138)
  int n = nb * 16 + (lane & 15);
  int klb = (lane >> 4) * 8;
  short8 frag;
  #pragma unroll
  for (int ii = 0; ii < 8; ii++) {
    float val;
    if (s < NS0) {                       // layer 0: k = i*48 + j
      int k = s * 32 + klb + ii;
      int i = k / 48, j = k - i * 48;
      val = (i < 39 && j < 39) ? W0[(i * 39 + j) * 128 + n] : 0.f;
    } else {                             // layer 1: k = i*64 + j, exact
      int k = (s - NS0) * 32 + klb + ii;
      int i = k >> 6, j = k & 63;
      val = W1[(i * 64 + j) * 128 + n];
    }
    frag[ii] = (short)f2bf(val);
  }
  wpk[fid] = frag;
}

// ---------------- fused CIN main kernel ----------------
__global__ __launch_bounds__(256, 3) void cin_main(const float* __restrict__ X,
                                                   const short8* __restrict__ wpk,
                                                   float* __restrict__ out) {
  extern __shared__ char smem[];
  float* V          = (float*)smem;                     // [128][41] f32
  char*  Zc         = smem + V_BYTES;                   // [128] rows x ZPITCH bytes, bf16
  unsigned short* H = (unsigned short*)(smem + V_BYTES); // [128][68] bf16, ALIASES Z

  const int t    = threadIdx.x;
  const int lane = t & 63;
  const int w    = t >> 6;
  const int wm   = w >> 1, wn = w & 1;     // 2x2 wave grid, each wave 64 rows x 64 cols
  const int l15  = lane & 15, l4 = lane >> 4;
  const int b0   = blockIdx.x * 8;

  // ---- stage x tile: x[b0+bl, i, d] -> V[bl*16+d][i]; V[:,39] = 0 pad ----
  const float* xb = X + (size_t)b0 * 624;   // 8*39*16 = 4992 floats
  for (int f = t * 4; f < 4992; f += 1024) {
    float4 v4 = *(const float4*)(xb + f);
    int bl = f / 624;
    int rem = f - bl * 624;
    int i = rem >> 4, d0 = rem & 15;
    int r = bl * 16 + d0;
    V[(r + 0) * VSTR + i] = v4.x;
    V[(r + 1) * VSTR + i] = v4.y;
    V[(r + 2) * VSTR + i] = v4.z;
    V[(r + 3) * VSTR + i] = v4.w;
  }
  if (t < 128) V[t * VSTR + 39] = 0.f;
  __syncthreads();

  // Z-gen ownership: thread t -> row rg = t>>1, j-half hf = t&1
  const int rg = t >> 1, hf = t & 1;
  const unsigned zrow = (unsigned)rg * ZPITCH;
  const unsigned zxor = (unsigned)((rg >> 3) & 1) << 4;

  // A-read base offsets per mi (swizzle folded in; +ss*64 never touches bit4)
  unsigned abase[4];
  #pragma unroll
  for (int mi = 0; mi < 4; mi++) {
    int row = wm * 64 + mi * 16 + l15;
    abase[mi] = ((unsigned)row * ZPITCH + (unsigned)l4 * 16) ^ ((unsigned)((row >> 3) & 1) << 4);
  }

  // register-cache v_j for layer-0 gen: j in [hf*24, hf*24+24), j>=39 -> 0
  float vj[24];
  #pragma unroll
  for (int jj = 0; jj < 24; jj++) {
    int j = hf * 24 + jj;
    vj[jj] = (j < 39) ? V[rg * VSTR + j] : 0.f;
  }

  f32x4 acc[4][4];
  #pragma unroll
  for (int mi = 0; mi < 4; mi++)
    #pragma unroll
    for (int ni = 0; ni < 4; ni++)
      acc[mi][ni] = (f32x4){0.f, 0.f, 0.f, 0.f};

  // ================= layer 0: 20 slabs x 96 k (2 i-blocks of 48) =================
  #pragma unroll 1
  for (int q = 0; q < 20; q++) {
    #pragma unroll
    for (int ib = 0; ib < 2; ib++) {
      float vi = V[rg * VSTR + (2 * q + ib)];
      #pragma unroll
      for (int g = 0; g < 3; g++) {
        float p0 = vi * vj[g * 8 + 0], p1 = vi * vj[g * 8 + 1];
        float p2 = vi * vj[g * 8 + 2], p3 = vi * vj[g * 8 + 3];
        float p4 = vi * vj[g * 8 + 4], p5 = vi * vj[g * 8 + 5];
        float p6 = vi * vj[g * 8 + 6], p7 = vi * vj[g * 8 + 7];
        uint4 pk = { cvt2(p0, p1), cvt2(p2, p3), cvt2(p4, p5), cvt2(p6, p7) };
        unsigned off = (zrow + (unsigned)(ib * 96 + hf * 48 + g * 16)) ^ zxor;
        *(uint4*)(Zc + off) = pk;
      }
    }
    __syncthreads();   // Z ready
    #pragma unroll
    for (int ss = 0; ss < 3; ss++) {
      int s = q * 3 + ss;
      short8 a[4];
      #pragma unroll
      for (int mi = 0; mi < 4; mi++)
        a[mi] = *(const short8*)(Zc + abase[mi] + (unsigned)ss * 64);
      #pragma unroll
      for (int ni = 0; ni < 4; ni++) {
        short8 bfrag = wpk[(s * 8 + wn * 4 + ni) * 64 + lane];
        #pragma unroll
        for (int mi = 0; mi < 4; mi++)
          acc[mi][ni] = __builtin_amdgcn_mfma_f32_16x16x32_bf16(a[mi], bfrag, acc[mi][ni], 0, 0, 0);
      }
    }
    __syncthreads();   // Z consumed (also protects epilogue H-aliasing after last q)
  }

  // ---- layer-0 epilogue: relu; cols 0..63 -> H (aliases Z); cols 64..127 -> out[b,0:64] ----
  if (wn == 0) {
    #pragma unroll
    for (int mi = 0; mi < 4; mi++)
      #pragma unroll
      for (int ni = 0; ni < 4; ni++)
        #pragma unroll
        for (int e = 0; e < 4; e++) {
          int row = wm * 64 + mi * 16 + l4 * 4 + e;
          int col = ni * 16 + l15;
          H[row * HSTR + col] = f2bf(fmaxf(acc[mi][ni][e], 0.f));
        }
  } else {
    #pragma unroll
    for (int mi = 0; mi < 4; mi++)
      #pragma unroll
      for (int ni = 0; ni < 4; ni++) {
        float s = fmaxf(acc[mi][ni][0], 0.f) + fmaxf(acc[mi][ni][1], 0.f)
                + fmaxf(acc[mi][ni][2], 0.f) + fmaxf(acc[mi][ni][3], 0.f);
        s += __shfl_xor(s, 16);
        s += __shfl_xor(s, 32);
        if (lane < 16)
          out[(size_t)(b0 + wm * 4 + mi) * 192 + ni * 16 + lane] = s;
      }
  }
  __syncthreads();   // H ready

  // register-cache h_j: j in [hf*32, hf*32+32)
  float hj[32];
  #pragma unroll
  for (int g = 0; g < 8; g++) {
    ushort4 pk = *(const ushort4*)(&H[rg * HSTR + hf * 32 + g * 4]);
    hj[g * 4 + 0] = ((float)0.f, __builtin_bit_cast(float, (unsigned)pk.x << 16));
    hj[g * 4 + 1] = __builtin_bit_cast(float, (unsigned)pk.y << 16);
    hj[g * 4 + 2] = __builtin_bit_cast(float, (unsigned)pk.z << 16);
    hj[g * 4 + 3] = __builtin_bit_cast(float, (unsigned)pk.w << 16);
  }
  __syncthreads();   // H consumed; Z region reusable

  // reset accumulators for layer 1
  #pragma unroll
  for (int mi = 0; mi < 4; mi++)
    #pragma unroll
    for (int ni = 0; ni < 4; ni++)
      acc[mi][ni] = (f32x4){0.f, 0.f, 0.f, 0.f};

  // ================= layer 1: 39 slabs x 64 k (1 i-block of 64) =================
  #pragma unroll 1
  for (int q = 0; q < 39; q++) {
    {
      float vi = V[rg * VSTR + q];
      #pragma unroll
      for (int g = 0; g < 4; g++) {
        float p0 = vi * hj[g * 8 + 0], p1 = vi * hj[g * 8 + 1];
        float p2 = vi * hj[g * 8 + 2], p3 = vi * hj[g * 8 + 3];
        float p4 = vi * hj[g * 8 + 4], p5 = vi * hj[g * 8 + 5];
        float p6 = vi * hj[g * 8 + 6], p7 = vi * hj[g * 8 + 7];
        uint4 pk = { cvt2(p0, p1), cvt2(p2, p3), cvt2(p4, p5), cvt2(p6, p7) };
        unsigned off = (zrow + (unsigned)(hf * 64 + g * 16)) ^ zxor;
        *(uint4*)(Zc + off) = pk;
      }
    }
    __syncthreads();
    #pragma unroll
    for (int ss = 0; ss < 2; ss++) {
      int s = NS0 + q * 2 + ss;
      short8 a[4];
      #pragma unroll
      for (int mi = 0; mi < 4; mi++)
        a[mi] = *(const short8*)(Zc + abase[mi] + (unsigned)ss * 64);
      #pragma unroll
      for (int ni = 0; ni < 4; ni++) {
        short8 bfrag = wpk[(s * 8 + wn * 4 + ni) * 64 + lane];
        #pragma unroll
        for (int mi = 0; mi < 4; mi++)
          acc[mi][ni] = __builtin_amdgcn_mfma_f32_16x16x32_bf16(a[mi], bfrag, acc[mi][ni], 0, 0, 0);
      }
    }
    __syncthreads();
  }

  // ---- layer-1 epilogue: relu, reduce over d, out[b, 64:192] ----
  #pragma unroll
  for (int mi = 0; mi < 4; mi++)
    #pragma unroll
    for (int ni = 0; ni < 4; ni++) {
      float s = fmaxf(acc[mi][ni][0], 0.f) + fmaxf(acc[mi][ni][1], 0.f)
              + fmaxf(acc[mi][ni][2], 0.f) + fmaxf(acc[mi][ni][3], 0.f);
      s += __shfl_xor(s, 16);
      s += __shfl_xor(s, 32);
      if (lane < 16)
        out[(size_t)(b0 + wm * 4 + mi) * 192 + 64 + wn * 64 + ni * 16 + lane] = s;
    }
}

extern "C" void kernel_launch(void* const* d_in, const int* in_sizes, int n_in,
                              void* d_out, int out_size, void* d_ws, size_t ws_size,
                              hipStream_t stream) {
  (void)in_sizes; (void)n_in; (void)out_size; (void)ws_size;
  const float* X  = (const float*)d_in[0];   // [8192,39,16]
  const float* W0 = (const float*)d_in[1];   // [1521,128]
  const float* W1 = (const float*)d_in[2];   // [2496,128]
  float* out = (float*)d_out;                // [8192,192]
  short8* wpk = (short8*)d_ws;               // packed bf16 W0|W1, 1.13 MB

  pack_w<<<(NFRAG + 255) / 256, 256, 0, stream>>>(W0, W1, wpk);
  cin_main<<<1024, 256, SMEM_BYTES, stream>>>(X, wpk, out);
}